// Round 1
// 531.532 us; speedup vs baseline: 1.0837x; 1.0837x over previous
//
#include <hip/hip_runtime.h>
#include <hip/hip_fp16.h>

// 192^3 single-step fluid solver, fp32 velocity.
// Layout: [c, i, j, k], k fastest.
// R6: advect re-tiled 2x2 (i,j) rows per block (768 thr). Halo read
//     amplification 9x -> 4x (763 -> 340 MB of L2/L3 traffic), occupancy
//     55% -> 75%, LDS rows padded to 196 floats so the four gather rows
//     hit distinct bank groups. Diffuse + fp16 pressure path unchanged.

constexpr int   N      = 192;
constexpr int   N2     = N * N;
constexpr int   N3     = N * N * N;
constexpr float GDT    = 9.81f * 0.01f;            // GRAV * DT
constexpr float SCL    = 0.01f / 0.1f;             // DT / H = 0.1
constexpr float ALPHA  = 0.01f * 0.01f / (0.1f * 0.1f);  // VISC*DT/H^2 = 0.01
constexpr float INVDIF = 1.0f / (1.0f + 6.0f * ALPHA);
constexpr float INV2H  = 1.0f / (2.0f * 0.1f);     // 5.0
constexpr float SIXTH  = 1.0f / 6.0f;

constexpr int NT4 = (N3 / 4) / 256;   // 6912 blocks, 4 cells/thread
constexpr int SLAB = NT4 / 8;         // 864 blocks per XCD i-slab

__device__ __forceinline__ int swz(int b) {
    return (b & 7) * SLAB + (b >> 3);
}

__device__ __forceinline__ void decomp(int id, int& i, int& j, int& k0) {
    i = id / N2;
    const int r = id - i * N2;
    j = r / N;
    k0 = r - j * N;
}

// ---- fp16 helpers (storage fp16, math fp32) ----
union H4u { ushort4 u; __half h[4]; };
__device__ __forceinline__ float4 ldh4(const __half* p) {
    H4u t; t.u = *(const ushort4*)p;
    return make_float4(__half2float(t.h[0]), __half2float(t.h[1]),
                       __half2float(t.h[2]), __half2float(t.h[3]));
}
__device__ __forceinline__ void sth4(__half* p, float x, float y, float z, float w) {
    H4u t;
    t.h[0] = __float2half(x); t.h[1] = __float2half(y);
    t.h[2] = __float2half(z); t.h[3] = __float2half(w);
    *(ushort4*)p = t.u;
}
__device__ __forceinline__ float ldh(const __half* p) { return __half2float(*p); }

// ---------------- advect (+gravity), 2x2-row LDS tile ----------------
// Block = 768 threads = four (i,j) k-rows (2x2 tile). Stage
// vin[c, i0-1..i0+2, j0-1..j0+2, :] = 48 rows. Row stride padded to 196
// floats: row step = 4 banks, i-step (4 rows) = 16 banks -> the four
// (lix,liy) gather candidates map to bank offsets {0,4,16,20}.
constexpr int RS    = 196;            // padded row stride (floats)
constexpr int TILEI = N / 2;          // 96 i-tiles
constexpr int TPS   = TILEI / 8;      // 12 i-tiles per XCD slab
constexpr int NBADV = (N / 2) * (N / 2);  // 9216 blocks

__global__ __launch_bounds__(768) void k_advect(const float* __restrict__ vin,
                                                float* __restrict__ vout) {
    __shared__ float s[48 * RS];      // 36.75 KB: [(c*4+di)*4+dj][k]

    const int lin = blockIdx.x;
    const int x   = lin & 7;                         // XCD slab
    const int q   = lin >> 3;
    const int il  = q % TPS;
    const int jt  = q / TPS;
    const int i0  = (x * TPS + il) * 2;
    const int j0  = jt * 2;

    // stage 48 rows x 48 float4 = 2304 float4, 3 per thread, coalesced
#pragma unroll
    for (int p = 0; p < 3; ++p) {
        const int f   = p * 768 + threadIdx.x;
        const int r   = f / 48;                      // 0..47
        const int c4  = f - r * 48;                  // 0..47
        const int c   = r >> 4;
        const int rem = r & 15;
        const int di  = rem >> 2;
        const int dj  = rem & 3;
        const int gi  = min(max(i0 + di - 1, 0), N - 1);
        const int gj  = min(max(j0 + dj - 1, 0), N - 1);
        *(float4*)&s[r * RS + c4 * 4] =
            *(const float4*)&vin[c * N3 + gi * N2 + gj * N + c4 * 4];
    }
    __syncthreads();

    const int t  = threadIdx.x / 192;                // 0..3, wave-uniform
    const int k  = threadIdx.x - t * 192;
    const int li = t >> 1;                           // 0..1
    const int lj = t & 1;
    const int i  = i0 + li;
    const int j  = j0 + lj;
    const int id = (i * N + j) * N + k;

    // center rows: (c, di=li+1, dj=lj+1)
    const int cr = ((li + 1) * 4 + (lj + 1)) * RS + k;
    const float vx = s[cr];
    const float vy = s[16 * RS + cr];
    const float vz = s[32 * RS + cr] - GDT;

    float px = (float)i - vx * SCL;
    float py = (float)j - vy * SCL;
    float pz = (float)k - vz * SCL;
    const float hi = (float)(N - 2);
    px = fminf(fmaxf(px, 0.0f), hi);
    py = fminf(fmaxf(py, 0.0f), hi);
    pz = fminf(fmaxf(pz, 0.0f), hi);

    const int ix = (int)px;
    const int iy = (int)py;
    const int iz = (int)pz;

    float g[3][8];
    const bool in = (ix >= i - 1) & (ix <= i) & (iy >= j - 1) & (iy <= j);
    if (in) {
        const int lix = ix - i0 + 1;                 // 0..2
        const int liy = iy - j0 + 1;                 // 0..2
#pragma unroll
        for (int c = 0; c < 3; ++c) {
            const int r00 = ((c * 16 + lix * 4 + liy)) * RS + iz;
            const int r01 = r00 + RS;                // dj+1
            const int r10 = r00 + 4 * RS;            // di+1
            const int r11 = r10 + RS;
            g[c][0] = s[r00];     g[c][1] = s[r00 + 1];
            g[c][2] = s[r01];     g[c][3] = s[r01 + 1];
            g[c][4] = s[r10];     g[c][5] = s[r10 + 1];
            g[c][6] = s[r11];     g[c][7] = s[r11 + 1];
        }
    } else {                                         // rare: left the window
        const int base = (ix * N + iy) * N + iz;
#pragma unroll
        for (int c = 0; c < 3; ++c) {
            const float* f = vin + c * N3 + base;
            g[c][0] = f[0];      g[c][1] = f[1];
            g[c][2] = f[N];      g[c][3] = f[N + 1];
            g[c][4] = f[N2];     g[c][5] = f[N2 + 1];
            g[c][6] = f[N2 + N]; g[c][7] = f[N2 + N + 1];
        }
    }

    const float wx1 = px - (float)ix, wy1 = py - (float)iy, wz1 = pz - (float)iz;
    const float wx0 = 1.0f - wx1,     wy0 = 1.0f - wy1,     wz0 = 1.0f - wz1;
    const float w000 = wx0 * wy0 * wz0;
    const float w001 = wx0 * wy0 * wz1;
    const float w010 = wx0 * wy1 * wz0;
    const float w011 = wx0 * wy1 * wz1;
    const float w100 = wx1 * wy0 * wz0;
    const float w101 = wx1 * wy0 * wz1;
    const float w110 = wx1 * wy1 * wz0;
    const float w111 = wx1 * wy1 * wz1;

#pragma unroll
    for (int c = 0; c < 3; ++c) {
        float r = g[c][0] * w000 + g[c][1] * w001
                + g[c][2] * w010 + g[c][3] * w011
                + g[c][4] * w100 + g[c][5] * w101
                + g[c][6] * w110 + g[c][7] * w111;
        if (c == 2) r -= GDT;
        vout[c * N3 + id] = r;
    }
}

// ---------------- diffuse, float4, component = blockIdx.y (unchanged) --------
__global__ __launch_bounds__(256) void k_diffuse4(const float* __restrict__ vin,
                                                  float* __restrict__ vout) {
    const int gtid = swz(blockIdx.x) * 256 + threadIdx.x;
    const int id   = gtid << 2;
    int i, j, k0; decomp(id, i, j, k0);
    const int b = blockIdx.y * N3 + id;

    const float4 c = *(const float4*)(vin + b);
    float4 out = c;
    if (i != 0 && i != N - 1 && j != 0 && j != N - 1) {
        const float4 ip = *(const float4*)(vin + b + N2);
        const float4 im = *(const float4*)(vin + b - N2);
        const float4 jp = *(const float4*)(vin + b + N);
        const float4 jm = *(const float4*)(vin + b - N);
        const float  km = (k0 > 0)     ? vin[b - 1] : 0.0f;
        const float  kp = (k0 < N - 4) ? vin[b + 4] : 0.0f;
        out.x = (c.x + ALPHA * (im.x + ip.x + jm.x + jp.x + km  + c.y)) * INVDIF;
        out.y = (c.y + ALPHA * (im.y + ip.y + jm.y + jp.y + c.x + c.z)) * INVDIF;
        out.z = (c.z + ALPHA * (im.z + ip.z + jm.z + jp.z + c.y + c.w)) * INVDIF;
        out.w = (c.w + ALPHA * (im.w + ip.w + jm.w + jp.w + c.z + kp )) * INVDIF;
        if (k0 == 0)     out.x = c.x;
        if (k0 == N - 4) out.w = c.w;
    }
    *(float4*)(vout + b) = out;
}

// ---------------- divergence: fp32 vel -> fp16 dv ----------------
__global__ __launch_bounds__(256) void k_div4(const float* __restrict__ v,
                                              __half* __restrict__ dv) {
    const int gtid = swz(blockIdx.x) * 256 + threadIdx.x;
    const int id   = gtid << 2;
    int i, j, k0; decomp(id, i, j, k0);

    float ox = 0.f, oy = 0.f, oz = 0.f, ow = 0.f;
    if (i != 0 && i != N - 1 && j != 0 && j != N - 1) {
        const float4 xp = *(const float4*)(v + id + N2);
        const float4 xm = *(const float4*)(v + id - N2);
        const float4 yp = *(const float4*)(v + N3 + id + N);
        const float4 ym = *(const float4*)(v + N3 + id - N);
        const float4 z  = *(const float4*)(v + 2 * N3 + id);
        const float  zm = (k0 > 0)     ? v[2 * N3 + id - 1] : 0.0f;
        const float  zp = (k0 < N - 4) ? v[2 * N3 + id + 4] : 0.0f;
        ox = ((xp.x - xm.x) + (yp.x - ym.x) + (z.y - zm )) * INV2H;
        oy = ((xp.y - xm.y) + (yp.y - ym.y) + (z.z - z.x)) * INV2H;
        oz = ((xp.z - xm.z) + (yp.z - ym.z) + (z.w - z.y)) * INV2H;
        ow = ((xp.w - xm.w) + (yp.w - ym.w) + (zp  - z.z)) * INV2H;
        if (k0 == 0)     ox = 0.f;
        if (k0 == N - 4) ow = 0.f;
    }
    sth4(dv + id, ox, oy, oz, ow);
}

// ---------------- pressure iterations 1+2 fused, fp16 io ----------------
__global__ __launch_bounds__(256) void k_p2_4(const __half* __restrict__ dv,
                                              __half* __restrict__ p) {
    const int gtid = swz(blockIdx.x) * 256 + threadIdx.x;
    const int id   = gtid << 2;
    int i, j, k0; decomp(id, i, j, k0);

    float ox = 0.f, oy = 0.f, oz = 0.f, ow = 0.f;
    if (i != 0 && i != N - 1 && j != 0 && j != N - 1) {
        const float4 c  = ldh4(dv + id);
        const float4 ip = ldh4(dv + id + N2);
        const float4 im = ldh4(dv + id - N2);
        const float4 jp = ldh4(dv + id + N);
        const float4 jm = ldh4(dv + id - N);
        const float  km = (k0 > 0)     ? ldh(dv + id - 1) : 0.0f;
        const float  kp = (k0 < N - 4) ? ldh(dv + id + 4) : 0.0f;
        ox = (c.x + (im.x + ip.x + jm.x + jp.x + km  + c.y) * SIXTH) * SIXTH;
        oy = (c.y + (im.y + ip.y + jm.y + jp.y + c.x + c.z) * SIXTH) * SIXTH;
        oz = (c.z + (im.z + ip.z + jm.z + jp.z + c.y + c.w) * SIXTH) * SIXTH;
        ow = (c.w + (im.w + ip.w + jm.w + jp.w + c.z + kp ) * SIXTH) * SIXTH;
        if (k0 == 0)     ox = 0.f;
        if (k0 == N - 4) ow = 0.f;
    }
    sth4(p + id, ox, oy, oz, ow);
}

// ---------------- pressure Jacobi sweep, fp16 io ----------------
__global__ __launch_bounds__(256) void k_jacobi4(const __half* __restrict__ pin,
                                                 const __half* __restrict__ dv,
                                                 __half* __restrict__ pout) {
    const int gtid = swz(blockIdx.x) * 256 + threadIdx.x;
    const int id   = gtid << 2;
    int i, j, k0; decomp(id, i, j, k0);

    float ox = 0.f, oy = 0.f, oz = 0.f, ow = 0.f;
    if (i != 0 && i != N - 1 && j != 0 && j != N - 1) {
        const float4 c  = ldh4(pin + id);
        const float4 ip = ldh4(pin + id + N2);
        const float4 im = ldh4(pin + id - N2);
        const float4 jp = ldh4(pin + id + N);
        const float4 jm = ldh4(pin + id - N);
        const float4 d  = ldh4(dv + id);
        const float  km = (k0 > 0)     ? ldh(pin + id - 1) : 0.0f;
        const float  kp = (k0 < N - 4) ? ldh(pin + id + 4) : 0.0f;
        ox = (d.x + im.x + ip.x + jm.x + jp.x + km  + c.y) * SIXTH;
        oy = (d.y + im.y + ip.y + jm.y + jp.y + c.x + c.z) * SIXTH;
        oz = (d.z + im.z + ip.z + jm.z + jp.z + c.y + c.w) * SIXTH;
        ow = (d.w + im.w + ip.w + jm.w + jp.w + c.z + kp ) * SIXTH;
        if (k0 == 0)     ox = 0.f;
        if (k0 == N - 4) ow = 0.f;
    }
    sth4(pout + id, ox, oy, oz, ow);
}

// ---------------- gradient subtract, fp16 p, fp32 vel in-place ---------------
__global__ __launch_bounds__(256) void k_grad4(float* __restrict__ vel,
                                               const __half* __restrict__ p) {
    const int gtid = swz(blockIdx.x) * 256 + threadIdx.x;
    const int id   = gtid << 2;
    int i, j, k0; decomp(id, i, j, k0);
    if (i == 0 || i == N - 1 || j == 0 || j == N - 1) return;

    const float4 xp = ldh4(p + id + N2);
    const float4 xm = ldh4(p + id - N2);
    const float4 yp = ldh4(p + id + N);
    const float4 ym = ldh4(p + id - N);
    const float4 c  = ldh4(p + id);
    const float  pm = (k0 > 0)     ? ldh(p + id - 1) : 0.0f;
    const float  pp = (k0 < N - 4) ? ldh(p + id + 4) : 0.0f;

    const bool bx = (k0 == 0);
    const bool bw = (k0 == N - 4);

    float4 v0 = *(float4*)(vel + id);
    if (!bx) v0.x -= (xp.x - xm.x) * INV2H;
             v0.y -= (xp.y - xm.y) * INV2H;
             v0.z -= (xp.z - xm.z) * INV2H;
    if (!bw) v0.w -= (xp.w - xm.w) * INV2H;
    *(float4*)(vel + id) = v0;

    float4 v1 = *(float4*)(vel + N3 + id);
    if (!bx) v1.x -= (yp.x - ym.x) * INV2H;
             v1.y -= (yp.y - ym.y) * INV2H;
             v1.z -= (yp.z - ym.z) * INV2H;
    if (!bw) v1.w -= (yp.w - ym.w) * INV2H;
    *(float4*)(vel + N3 + id) = v1;

    float4 v2 = *(float4*)(vel + 2 * N3 + id);
    if (!bx) v2.x -= (c.y - pm ) * INV2H;
             v2.y -= (c.z - c.x) * INV2H;
             v2.z -= (c.w - c.y) * INV2H;
    if (!bw) v2.w -= (pp  - c.z) * INV2H;
    *(float4*)(vel + 2 * N3 + id) = v2;
}

extern "C" void kernel_launch(void* const* d_in, const int* in_sizes, int n_in,
                              void* d_out, int out_size, void* d_ws, size_t ws_size,
                              hipStream_t stream) {
    const float* vin  = (const float*)d_in[0];
    float*       vout = (float*)d_out;
    float*       ws   = (float*)d_ws;

    // ws layout: phase 1 velB = fp32 ws[0..3N3);
    // phase 2 (velB dead): fp16 dv = hws[0..N3), pA = hws[N3..2N3), pB = hws[2N3..3N3)
    float*  velB = ws;
    __half* hws  = (__half*)d_ws;
    __half* dv   = hws;
    __half* pA   = hws + N3;
    __half* pB   = hws + 2 * N3;

    const dim3 blkA(768, 1, 1);
    const dim3 gridA(NBADV, 1, 1);
    const dim3 blk4(256, 1, 1);
    const dim3 grid4_1(NT4, 1, 1);
    const dim3 grid4_3(NT4, 3, 1);

    // gravity + advect: vin -> velB
    k_advect<<<gridA, blkA, 0, stream>>>(vin, velB);

    // 5 diffusion sweeps, ping-pong; ends in vout
    k_diffuse4<<<grid4_3, blk4, 0, stream>>>(velB, vout);
    k_diffuse4<<<grid4_3, blk4, 0, stream>>>(vout, velB);
    k_diffuse4<<<grid4_3, blk4, 0, stream>>>(velB, vout);
    k_diffuse4<<<grid4_3, blk4, 0, stream>>>(vout, velB);
    k_diffuse4<<<grid4_3, blk4, 0, stream>>>(velB, vout);

    // projection (fp16 pressure path)
    k_div4<<<grid4_1, blk4, 0, stream>>>(vout, dv);
    k_p2_4<<<grid4_1, blk4, 0, stream>>>(dv, pA);        // iterations 1-2
    __half* pin  = pA;
    __half* pout = pB;
    for (int s = 0; s < 18; ++s) {                       // iterations 3..20
        k_jacobi4<<<grid4_1, blk4, 0, stream>>>(pin, dv, pout);
        __half* t = pin; pin = pout; pout = t;
    }
    k_grad4<<<grid4_1, blk4, 0, stream>>>(vout, pin);    // in-place on d_out
}

// Round 2
// 518.214 us; speedup vs baseline: 1.1115x; 1.0257x over previous
//
#include <hip/hip_runtime.h>
#include <hip/hip_fp16.h>

// 192^3 single-step fluid solver.
// Layout: [c, i, j, k], k fastest.
// R7: velocity intermediates stored fp16 (math fp32). advect -> fp16 velA;
//     diffuse sweeps 1-4 fp16->fp16 ping-pong; sweep 5 fp16->fp32 vout.
//     Halves the ~850 MB fp32 diffuse-phase traffic. Pressure path (fp16)
//     and advect tiling (2x2 rows, 768 thr) unchanged from R6.

constexpr int   N      = 192;
constexpr int   N2     = N * N;
constexpr int   N3     = N * N * N;
constexpr float GDT    = 9.81f * 0.01f;            // GRAV * DT
constexpr float SCL    = 0.01f / 0.1f;             // DT / H = 0.1
constexpr float ALPHA  = 0.01f * 0.01f / (0.1f * 0.1f);  // VISC*DT/H^2 = 0.01
constexpr float INVDIF = 1.0f / (1.0f + 6.0f * ALPHA);
constexpr float INV2H  = 1.0f / (2.0f * 0.1f);     // 5.0
constexpr float SIXTH  = 1.0f / 6.0f;

constexpr int NT4 = (N3 / 4) / 256;   // 6912 blocks, 4 cells/thread
constexpr int SLAB = NT4 / 8;         // 864 blocks per XCD i-slab

__device__ __forceinline__ int swz(int b) {
    return (b & 7) * SLAB + (b >> 3);
}

__device__ __forceinline__ void decomp(int id, int& i, int& j, int& k0) {
    i = id / N2;
    const int r = id - i * N2;
    j = r / N;
    k0 = r - j * N;
}

// ---- fp16 helpers (storage fp16, math fp32) ----
union H4u { ushort4 u; __half h[4]; };
__device__ __forceinline__ float4 ldh4(const __half* p) {
    H4u t; t.u = *(const ushort4*)p;
    return make_float4(__half2float(t.h[0]), __half2float(t.h[1]),
                       __half2float(t.h[2]), __half2float(t.h[3]));
}
__device__ __forceinline__ void sth4(__half* p, float x, float y, float z, float w) {
    H4u t;
    t.h[0] = __float2half(x); t.h[1] = __float2half(y);
    t.h[2] = __float2half(z); t.h[3] = __float2half(w);
    *(ushort4*)p = t.u;
}
__device__ __forceinline__ float ldh(const __half* p) { return __half2float(*p); }

// ---------------- advect (+gravity), 2x2-row LDS tile, fp16 out ----------------
constexpr int RS    = 196;            // padded row stride (floats)
constexpr int TILEI = N / 2;          // 96 i-tiles
constexpr int TPS   = TILEI / 8;      // 12 i-tiles per XCD slab
constexpr int NBADV = (N / 2) * (N / 2);  // 9216 blocks

__global__ __launch_bounds__(768) void k_advect(const float* __restrict__ vin,
                                                __half* __restrict__ vout) {
    __shared__ float s[48 * RS];      // 36.75 KB: [(c*4+di)*4+dj][k]

    const int lin = blockIdx.x;
    const int x   = lin & 7;                         // XCD slab
    const int q   = lin >> 3;
    const int il  = q % TPS;
    const int jt  = q / TPS;
    const int i0  = (x * TPS + il) * 2;
    const int j0  = jt * 2;

    // stage 48 rows x 48 float4 = 2304 float4, 3 per thread, coalesced
#pragma unroll
    for (int p = 0; p < 3; ++p) {
        const int f   = p * 768 + threadIdx.x;
        const int r   = f / 48;                      // 0..47
        const int c4  = f - r * 48;                  // 0..47
        const int c   = r >> 4;
        const int rem = r & 15;
        const int di  = rem >> 2;
        const int dj  = rem & 3;
        const int gi  = min(max(i0 + di - 1, 0), N - 1);
        const int gj  = min(max(j0 + dj - 1, 0), N - 1);
        *(float4*)&s[r * RS + c4 * 4] =
            *(const float4*)&vin[c * N3 + gi * N2 + gj * N + c4 * 4];
    }
    __syncthreads();

    const int t  = threadIdx.x / 192;                // 0..3, wave-uniform
    const int k  = threadIdx.x - t * 192;
    const int li = t >> 1;                           // 0..1
    const int lj = t & 1;
    const int i  = i0 + li;
    const int j  = j0 + lj;
    const int id = (i * N + j) * N + k;

    // center rows: (c, di=li+1, dj=lj+1)
    const int cr = ((li + 1) * 4 + (lj + 1)) * RS + k;
    const float vx = s[cr];
    const float vy = s[16 * RS + cr];
    const float vz = s[32 * RS + cr] - GDT;

    float px = (float)i - vx * SCL;
    float py = (float)j - vy * SCL;
    float pz = (float)k - vz * SCL;
    const float hi = (float)(N - 2);
    px = fminf(fmaxf(px, 0.0f), hi);
    py = fminf(fmaxf(py, 0.0f), hi);
    pz = fminf(fmaxf(pz, 0.0f), hi);

    const int ix = (int)px;
    const int iy = (int)py;
    const int iz = (int)pz;

    float g[3][8];
    const bool in = (ix >= i - 1) & (ix <= i) & (iy >= j - 1) & (iy <= j);
    if (in) {
        const int lix = ix - i0 + 1;                 // 0..2
        const int liy = iy - j0 + 1;                 // 0..2
#pragma unroll
        for (int c = 0; c < 3; ++c) {
            const int r00 = ((c * 16 + lix * 4 + liy)) * RS + iz;
            const int r01 = r00 + RS;                // dj+1
            const int r10 = r00 + 4 * RS;            // di+1
            const int r11 = r10 + RS;
            g[c][0] = s[r00];     g[c][1] = s[r00 + 1];
            g[c][2] = s[r01];     g[c][3] = s[r01 + 1];
            g[c][4] = s[r10];     g[c][5] = s[r10 + 1];
            g[c][6] = s[r11];     g[c][7] = s[r11 + 1];
        }
    } else {                                         // rare: left the window
        const int base = (ix * N + iy) * N + iz;
#pragma unroll
        for (int c = 0; c < 3; ++c) {
            const float* f = vin + c * N3 + base;
            g[c][0] = f[0];      g[c][1] = f[1];
            g[c][2] = f[N];      g[c][3] = f[N + 1];
            g[c][4] = f[N2];     g[c][5] = f[N2 + 1];
            g[c][6] = f[N2 + N]; g[c][7] = f[N2 + N + 1];
        }
    }

    const float wx1 = px - (float)ix, wy1 = py - (float)iy, wz1 = pz - (float)iz;
    const float wx0 = 1.0f - wx1,     wy0 = 1.0f - wy1,     wz0 = 1.0f - wz1;
    const float w000 = wx0 * wy0 * wz0;
    const float w001 = wx0 * wy0 * wz1;
    const float w010 = wx0 * wy1 * wz0;
    const float w011 = wx0 * wy1 * wz1;
    const float w100 = wx1 * wy0 * wz0;
    const float w101 = wx1 * wy0 * wz1;
    const float w110 = wx1 * wy1 * wz0;
    const float w111 = wx1 * wy1 * wz1;

#pragma unroll
    for (int c = 0; c < 3; ++c) {
        float r = g[c][0] * w000 + g[c][1] * w001
                + g[c][2] * w010 + g[c][3] * w011
                + g[c][4] * w100 + g[c][5] * w101
                + g[c][6] * w110 + g[c][7] * w111;
        if (c == 2) r -= GDT;
        vout[c * N3 + id] = __float2half(r);
    }
}

// ---------------- diffuse, fp16 -> fp16, component = blockIdx.y --------------
__global__ __launch_bounds__(256) void k_diffh(const __half* __restrict__ vin,
                                               __half* __restrict__ vout) {
    const int gtid = swz(blockIdx.x) * 256 + threadIdx.x;
    const int id   = gtid << 2;
    int i, j, k0; decomp(id, i, j, k0);
    const int b = blockIdx.y * N3 + id;

    const float4 c = ldh4(vin + b);
    float4 out = c;
    if (i != 0 && i != N - 1 && j != 0 && j != N - 1) {
        const float4 ip = ldh4(vin + b + N2);
        const float4 im = ldh4(vin + b - N2);
        const float4 jp = ldh4(vin + b + N);
        const float4 jm = ldh4(vin + b - N);
        const float  km = (k0 > 0)     ? ldh(vin + b - 1) : 0.0f;
        const float  kp = (k0 < N - 4) ? ldh(vin + b + 4) : 0.0f;
        out.x = (c.x + ALPHA * (im.x + ip.x + jm.x + jp.x + km  + c.y)) * INVDIF;
        out.y = (c.y + ALPHA * (im.y + ip.y + jm.y + jp.y + c.x + c.z)) * INVDIF;
        out.z = (c.z + ALPHA * (im.z + ip.z + jm.z + jp.z + c.y + c.w)) * INVDIF;
        out.w = (c.w + ALPHA * (im.w + ip.w + jm.w + jp.w + c.z + kp )) * INVDIF;
        if (k0 == 0)     out.x = c.x;
        if (k0 == N - 4) out.w = c.w;
    }
    sth4(vout + b, out.x, out.y, out.z, out.w);
}

// ---------------- diffuse, fp16 -> fp32 (final sweep) ----------------
__global__ __launch_bounds__(256) void k_diffhf(const __half* __restrict__ vin,
                                                float* __restrict__ vout) {
    const int gtid = swz(blockIdx.x) * 256 + threadIdx.x;
    const int id   = gtid << 2;
    int i, j, k0; decomp(id, i, j, k0);
    const int b = blockIdx.y * N3 + id;

    const float4 c = ldh4(vin + b);
    float4 out = c;
    if (i != 0 && i != N - 1 && j != 0 && j != N - 1) {
        const float4 ip = ldh4(vin + b + N2);
        const float4 im = ldh4(vin + b - N2);
        const float4 jp = ldh4(vin + b + N);
        const float4 jm = ldh4(vin + b - N);
        const float  km = (k0 > 0)     ? ldh(vin + b - 1) : 0.0f;
        const float  kp = (k0 < N - 4) ? ldh(vin + b + 4) : 0.0f;
        out.x = (c.x + ALPHA * (im.x + ip.x + jm.x + jp.x + km  + c.y)) * INVDIF;
        out.y = (c.y + ALPHA * (im.y + ip.y + jm.y + jp.y + c.x + c.z)) * INVDIF;
        out.z = (c.z + ALPHA * (im.z + ip.z + jm.z + jp.z + c.y + c.w)) * INVDIF;
        out.w = (c.w + ALPHA * (im.w + ip.w + jm.w + jp.w + c.z + kp )) * INVDIF;
        if (k0 == 0)     out.x = c.x;
        if (k0 == N - 4) out.w = c.w;
    }
    *(float4*)(vout + b) = out;
}

// ---------------- divergence: fp32 vel -> fp16 dv ----------------
__global__ __launch_bounds__(256) void k_div4(const float* __restrict__ v,
                                              __half* __restrict__ dv) {
    const int gtid = swz(blockIdx.x) * 256 + threadIdx.x;
    const int id   = gtid << 2;
    int i, j, k0; decomp(id, i, j, k0);

    float ox = 0.f, oy = 0.f, oz = 0.f, ow = 0.f;
    if (i != 0 && i != N - 1 && j != 0 && j != N - 1) {
        const float4 xp = *(const float4*)(v + id + N2);
        const float4 xm = *(const float4*)(v + id - N2);
        const float4 yp = *(const float4*)(v + N3 + id + N);
        const float4 ym = *(const float4*)(v + N3 + id - N);
        const float4 z  = *(const float4*)(v + 2 * N3 + id);
        const float  zm = (k0 > 0)     ? v[2 * N3 + id - 1] : 0.0f;
        const float  zp = (k0 < N - 4) ? v[2 * N3 + id + 4] : 0.0f;
        ox = ((xp.x - xm.x) + (yp.x - ym.x) + (z.y - zm )) * INV2H;
        oy = ((xp.y - xm.y) + (yp.y - ym.y) + (z.z - z.x)) * INV2H;
        oz = ((xp.z - xm.z) + (yp.z - ym.z) + (z.w - z.y)) * INV2H;
        ow = ((xp.w - xm.w) + (yp.w - ym.w) + (zp  - z.z)) * INV2H;
        if (k0 == 0)     ox = 0.f;
        if (k0 == N - 4) ow = 0.f;
    }
    sth4(dv + id, ox, oy, oz, ow);
}

// ---------------- pressure iterations 1+2 fused, fp16 io ----------------
__global__ __launch_bounds__(256) void k_p2_4(const __half* __restrict__ dv,
                                              __half* __restrict__ p) {
    const int gtid = swz(blockIdx.x) * 256 + threadIdx.x;
    const int id   = gtid << 2;
    int i, j, k0; decomp(id, i, j, k0);

    float ox = 0.f, oy = 0.f, oz = 0.f, ow = 0.f;
    if (i != 0 && i != N - 1 && j != 0 && j != N - 1) {
        const float4 c  = ldh4(dv + id);
        const float4 ip = ldh4(dv + id + N2);
        const float4 im = ldh4(dv + id - N2);
        const float4 jp = ldh4(dv + id + N);
        const float4 jm = ldh4(dv + id - N);
        const float  km = (k0 > 0)     ? ldh(dv + id - 1) : 0.0f;
        const float  kp = (k0 < N - 4) ? ldh(dv + id + 4) : 0.0f;
        ox = (c.x + (im.x + ip.x + jm.x + jp.x + km  + c.y) * SIXTH) * SIXTH;
        oy = (c.y + (im.y + ip.y + jm.y + jp.y + c.x + c.z) * SIXTH) * SIXTH;
        oz = (c.z + (im.z + ip.z + jm.z + jp.z + c.y + c.w) * SIXTH) * SIXTH;
        ow = (c.w + (im.w + ip.w + jm.w + jp.w + c.z + kp ) * SIXTH) * SIXTH;
        if (k0 == 0)     ox = 0.f;
        if (k0 == N - 4) ow = 0.f;
    }
    sth4(p + id, ox, oy, oz, ow);
}

// ---------------- pressure Jacobi sweep, fp16 io ----------------
__global__ __launch_bounds__(256) void k_jacobi4(const __half* __restrict__ pin,
                                                 const __half* __restrict__ dv,
                                                 __half* __restrict__ pout) {
    const int gtid = swz(blockIdx.x) * 256 + threadIdx.x;
    const int id   = gtid << 2;
    int i, j, k0; decomp(id, i, j, k0);

    float ox = 0.f, oy = 0.f, oz = 0.f, ow = 0.f;
    if (i != 0 && i != N - 1 && j != 0 && j != N - 1) {
        const float4 c  = ldh4(pin + id);
        const float4 ip = ldh4(pin + id + N2);
        const float4 im = ldh4(pin + id - N2);
        const float4 jp = ldh4(pin + id + N);
        const float4 jm = ldh4(pin + id - N);
        const float4 d  = ldh4(dv + id);
        const float  km = (k0 > 0)     ? ldh(pin + id - 1) : 0.0f;
        const float  kp = (k0 < N - 4) ? ldh(pin + id + 4) : 0.0f;
        ox = (d.x + im.x + ip.x + jm.x + jp.x + km  + c.y) * SIXTH;
        oy = (d.y + im.y + ip.y + jm.y + jp.y + c.x + c.z) * SIXTH;
        oz = (d.z + im.z + ip.z + jm.z + jp.z + c.y + c.w) * SIXTH;
        ow = (d.w + im.w + ip.w + jm.w + jp.w + c.z + kp ) * SIXTH;
        if (k0 == 0)     ox = 0.f;
        if (k0 == N - 4) ow = 0.f;
    }
    sth4(pout + id, ox, oy, oz, ow);
}

// ---------------- gradient subtract, fp16 p, fp32 vel in-place ---------------
__global__ __launch_bounds__(256) void k_grad4(float* __restrict__ vel,
                                               const __half* __restrict__ p) {
    const int gtid = swz(blockIdx.x) * 256 + threadIdx.x;
    const int id   = gtid << 2;
    int i, j, k0; decomp(id, i, j, k0);
    if (i == 0 || i == N - 1 || j == 0 || j == N - 1) return;

    const float4 xp = ldh4(p + id + N2);
    const float4 xm = ldh4(p + id - N2);
    const float4 yp = ldh4(p + id + N);
    const float4 ym = ldh4(p + id - N);
    const float4 c  = ldh4(p + id);
    const float  pm = (k0 > 0)     ? ldh(p + id - 1) : 0.0f;
    const float  pp = (k0 < N - 4) ? ldh(p + id + 4) : 0.0f;

    const bool bx = (k0 == 0);
    const bool bw = (k0 == N - 4);

    float4 v0 = *(float4*)(vel + id);
    if (!bx) v0.x -= (xp.x - xm.x) * INV2H;
             v0.y -= (xp.y - xm.y) * INV2H;
             v0.z -= (xp.z - xm.z) * INV2H;
    if (!bw) v0.w -= (xp.w - xm.w) * INV2H;
    *(float4*)(vel + id) = v0;

    float4 v1 = *(float4*)(vel + N3 + id);
    if (!bx) v1.x -= (yp.x - ym.x) * INV2H;
             v1.y -= (yp.y - ym.y) * INV2H;
             v1.z -= (yp.z - ym.z) * INV2H;
    if (!bw) v1.w -= (yp.w - ym.w) * INV2H;
    *(float4*)(vel + N3 + id) = v1;

    float4 v2 = *(float4*)(vel + 2 * N3 + id);
    if (!bx) v2.x -= (c.y - pm ) * INV2H;
             v2.y -= (c.z - c.x) * INV2H;
             v2.z -= (c.w - c.y) * INV2H;
    if (!bw) v2.w -= (pp  - c.z) * INV2H;
    *(float4*)(vel + 2 * N3 + id) = v2;
}

extern "C" void kernel_launch(void* const* d_in, const int* in_sizes, int n_in,
                              void* d_out, int out_size, void* d_ws, size_t ws_size,
                              hipStream_t stream) {
    const float* vin  = (const float*)d_in[0];
    float*       vout = (float*)d_out;

    // ws layout (fp16 halves):
    //   phase 1: velA = hws[0..3N3), velB = hws[3N3..6N3)   (fp16 velocity)
    //   phase 2 (vel buffers dead after final diffuse):
    //            dv = hws[0..N3), pA = hws[N3..2N3), pB = hws[2N3..3N3)
    __half* hws  = (__half*)d_ws;
    __half* velA = hws;
    __half* velB = hws + 3 * N3;
    __half* dv   = hws;
    __half* pA   = hws + N3;
    __half* pB   = hws + 2 * N3;

    const dim3 blkA(768, 1, 1);
    const dim3 gridA(NBADV, 1, 1);
    const dim3 blk4(256, 1, 1);
    const dim3 grid4_1(NT4, 1, 1);
    const dim3 grid4_3(NT4, 3, 1);

    // gravity + advect: vin (fp32) -> velA (fp16)
    k_advect<<<gridA, blkA, 0, stream>>>(vin, velA);

    // 5 diffusion sweeps: 4x fp16->fp16, final fp16->fp32 into vout
    k_diffh <<<grid4_3, blk4, 0, stream>>>(velA, velB);
    k_diffh <<<grid4_3, blk4, 0, stream>>>(velB, velA);
    k_diffh <<<grid4_3, blk4, 0, stream>>>(velA, velB);
    k_diffh <<<grid4_3, blk4, 0, stream>>>(velB, velA);
    k_diffhf<<<grid4_3, blk4, 0, stream>>>(velA, vout);

    // projection (fp16 pressure path); velA/velB dead -> reuse as dv/pA/pB
    k_div4<<<grid4_1, blk4, 0, stream>>>(vout, dv);
    k_p2_4<<<grid4_1, blk4, 0, stream>>>(dv, pA);        // iterations 1-2
    __half* pin  = pA;
    __half* pout = pB;
    for (int s = 0; s < 18; ++s) {                       // iterations 3..20
        k_jacobi4<<<grid4_1, blk4, 0, stream>>>(pin, dv, pout);
        __half* t = pin; pin = pout; pout = t;
    }
    k_grad4<<<grid4_1, blk4, 0, stream>>>(vout, pin);    // in-place on d_out
}